// Round 1
// 346.262 us; speedup vs baseline: 1.0402x; 1.0402x over previous
//
#include <hip/hip_runtime.h>

#define BB 16
#define ENC 64
#define HH 96
#define EE 128
#define VV 32000

__device__ __forceinline__ float tanh_fast(float x) {
    // exact at saturation: exp(2x)->inf => 1; ->0 => -1
    float e = __expf(2.f * x);
    return 1.f - 2.f / (e + 1.f);
}
__device__ __forceinline__ float sigmoid_fast(float x) {
    return 1.f / (1.f + __expf(-x));
}

// ---------------------------------------------------------------------------
// K0: partial enc_feat. part[ic][b][o][x] = sum_{i in chunk, kw} attn_w[o,i,47,kw]
//     * encpad[b,i,x+kw].  (conv kh collapses to 47: input height 1, pad(47,48))
// grid 1024 = b(16) * otile(8; 8 o) * ichunk(8; 8 i), 128 threads.
// Compute: lane = (og = t&7 -> one o row, xo = t>>3 -> 8-wide x strip).
// Rolling 3xfloat4 window over E => 1 E b128 + 1 W b128 per 32 FMA (was 12 LDS).
// Wb padded to stride 100 floats so the 8 og rows hit distinct bank quads.
// Blocks with b==0,ot==0 also extract cvg_w[:,:,0,47] -> cvgw47.
// ---------------------------------------------------------------------------
__global__ __launch_bounds__(128) void k_encfeat(
    const float* __restrict__ enc,      // (B,ENC,H)
    const float* __restrict__ attn_w,   // (ENC,ENC,H,H)
    const float* __restrict__ cvg_w,    // (ENC,ENC,1,H)
    float* __restrict__ part,           // (8,B,ENC,H) partial sums
    float* __restrict__ cvgw47)         // (ENC,ENC)
{
    int blk = blockIdx.x;
    int b   = blk >> 6;
    int ot  = (blk >> 3) & 7;
    int ic  = blk & 7;
    int o0  = ot * 8;
    int i0  = ic * 8;
    int t   = threadIdx.x;

    __shared__ __align__(16) float encS[8 * 192];      // 8 padded rows
    __shared__ __align__(16) float Wb[8 * 8 * 100];    // [i][o][k], stride 100

    for (int f = t; f < 8 * 192; f += 128) encS[f] = 0.f;
    __syncthreads();
    for (int f = t; f < 8 * 96; f += 128) {
        int i = f / 96, j = f - i * 96;
        encS[i * 192 + 47 + j] = enc[(size_t)((b * ENC + i0 + i) * 96) + j];
    }
    // stage weights: 6144 floats = 1536 float4, coalesced (12 per thread)
    for (int f4 = t; f4 < 1536; f4 += 128) {
        int o = f4 / 192;
        int r = f4 - o * 192;
        int i = r / 24, kq = r - i * 24;
        float4 q = *(const float4*)(attn_w +
            (size_t)((o0 + o) * ENC + (i0 + i)) * (96 * 96) + 47 * 96 + 4 * kq);
        *(float4*)&Wb[(i * 8 + o) * 100 + 4 * kq] = q;
    }
    // side job: cvgw47 extraction (8 blocks cover 4096 elems)
    if (b == 0 && ot == 0) {
        #pragma unroll
        for (int j = 0; j < 4; ++j) {
            int e = ic * 512 + j * 128 + t;
            cvgw47[e] = cvg_w[(size_t)e * 96 + 47];
        }
    }
    __syncthreads();

    if (t < 96) {
        int og = t & 7;              // one o row per lane
        int x0 = (t >> 3) * 8;       // 8-wide x strip
        float4 a0 = make_float4(0.f, 0.f, 0.f, 0.f);
        float4 a1 = make_float4(0.f, 0.f, 0.f, 0.f);
        for (int i = 0; i < 8; ++i) {
            const float* er = &encS[i * 192 + x0];
            const float* wr = &Wb[(i * 8 + og) * 100];
            float4 eA = *(const float4*)(er);
            float4 eB = *(const float4*)(er + 4);
            #pragma unroll 4
            for (int c = 0; c < 24; ++c) {
                float4 eC = *(const float4*)(er + 4 * c + 8);
                float4 q  = *(const float4*)(wr + 4 * c);
                a0.x += q.x * eA.x + q.y * eA.y + q.z * eA.z + q.w * eA.w;
                a0.y += q.x * eA.y + q.y * eA.z + q.z * eA.w + q.w * eB.x;
                a0.z += q.x * eA.z + q.y * eA.w + q.z * eB.x + q.w * eB.y;
                a0.w += q.x * eA.w + q.y * eB.x + q.z * eB.y + q.w * eB.z;
                a1.x += q.x * eB.x + q.y * eB.y + q.z * eB.z + q.w * eB.w;
                a1.y += q.x * eB.y + q.y * eB.z + q.z * eB.w + q.w * eC.x;
                a1.z += q.x * eB.z + q.y * eB.w + q.z * eC.x + q.w * eC.y;
                a1.w += q.x * eB.w + q.y * eC.x + q.z * eC.y + q.w * eC.z;
                eA = eB; eB = eC;
            }
        }
        float* outr = part + ((size_t)(ic * 16 + b) * 64 + o0 + og) * 96 + x0;
        *(float4*)(outr)     = a0;
        *(float4*)(outr + 4) = a1;
    }
}

// ---------------------------------------------------------------------------
// cooperative matvec: 4 lanes per output row, float4 loads, shuffle reduce.
// ---------------------------------------------------------------------------
__device__ __forceinline__ void matvec4(int g, int q, int nout, int nk,
    const float* __restrict__ W, int ldw, const float* __restrict__ bias,
    const float* __restrict__ xv, float* __restrict__ y)
{
    for (int j = g; j < nout; j += 64) {
        const float* wr = W + (size_t)j * ldw;
        float s = 0.f;
        for (int m = q; m < nk / 4; m += 4) {
            float4 wq = *(const float4*)(wr + 4 * m);
            s += wq.x * xv[4 * m] + wq.y * xv[4 * m + 1]
               + wq.z * xv[4 * m + 2] + wq.w * xv[4 * m + 3];
        }
        s += __shfl_xor(s, 1);
        s += __shfl_xor(s, 2);
        if (q == 0) y[j] = s + bias[j];
    }
}

// ---------------------------------------------------------------------------
// K1: fused attn1 + GRU + attn2 + pre-output, one block (256 thr) per b.
// ---------------------------------------------------------------------------
__global__ __launch_bounds__(256) void k_fused(
    const float* __restrict__ enc, const int* __restrict__ ids,
    const float* __restrict__ hidden, const float* __restrict__ coverage,
    const float* __restrict__ emb,
    const float* __restrict__ W_dec, const float* __restrict__ b_dec,
    const float* __restrict__ attn_b,
    const float* __restrict__ cvgw47, const float* __restrict__ cvg_b,
    const float* __restrict__ vvec,
    const float* __restrict__ W_new, const float* __restrict__ b_new,
    const float* __restrict__ w_ih, const float* __restrict__ w_hh,
    const float* __restrict__ b_ih, const float* __restrict__ b_hh,
    const float* __restrict__ W_pre, const float* __restrict__ b_pre,
    const float* __restrict__ part, float* __restrict__ oG,
    float* __restrict__ out_hidden, float* __restrict__ out_ctx2,
    float* __restrict__ out_aw2, float* __restrict__ out_cov2)
{
    int b = blockIdx.x, t = threadIdx.x;
    int g = t >> 2, q = t & 3;

    __shared__ __align__(16) float efS[ENC * HH];    // summed enc_feat slice
    __shared__ __align__(16) float encS[ENC * HH];   // enc slice
    __shared__ float hS[HH], vS[HH], decS[HH], ctxS[HH], xS[HH], h2S[HH], ctx2S[HH];
    __shared__ float covS[ENC], cvgS[ENC], sS[ENC], awS[ENC];
    __shared__ float embS[EE];
    __shared__ __align__(16) float xcatS[EE + HH];
    __shared__ float giS[3 * HH], ghS[3 * HH];

    {   // vectorized 8-way partial sum + enc staging (1536 float4)
        const float4* enc4 = (const float4*)(enc + (size_t)b * ENC * HH);
        float4* efS4  = (float4*)efS;
        float4* encS4 = (float4*)encS;
        for (int f = t; f < (ENC * HH) / 4; f += 256) {
            float4 s = make_float4(0.f, 0.f, 0.f, 0.f);
            #pragma unroll
            for (int ic = 0; ic < 8; ++ic) {
                const float4 p = *(const float4*)(part +
                    (size_t)(ic * 16 + b) * (ENC * HH) + 4 * f);
                s.x += p.x; s.y += p.y; s.z += p.z; s.w += p.w;
            }
            efS4[f]  = s;
            encS4[f] = enc4[f];
        }
    }
    if (t < HH) { hS[t] = hidden[b * HH + t]; vS[t] = vvec[b * HH + t]; }
    if (t >= 96 && t < 160) covS[t - 96] = coverage[b * ENC + (t - 96)];
    if (t >= 128 && t < 256) embS[t - 128] = emb[(size_t)ids[b] * EE + (t - 128)];
    __syncthreads();

    // ======== attention pass 1 ========
    matvec4(g, q, HH, HH, W_dec, HH, b_dec, hS, decS);
    matvec4(g, q, ENC, ENC, cvgw47, ENC, cvg_b, covS, cvgS);
    __syncthreads();
    {
        int e = g;
        float base = attn_b[e] + cvgS[e];
        const float* efr = &efS[e * HH];
        float s = 0.f;
        for (int m = q; m < 24; m += 4) {
            #pragma unroll
            for (int u = 0; u < 4; ++u) {
                int xx = 4 * m + u;
                s += tanh_fast(efr[xx] + decS[xx] + base) * vS[xx];
            }
        }
        s += __shfl_xor(s, 1); s += __shfl_xor(s, 2);
        if (q == 0) sS[e] = s;
    }
    __syncthreads();
    if (t < ENC) {
        float m = -1e30f;
        for (int j = 0; j < ENC; ++j) m = fmaxf(m, sS[j]);
        float sum = 0.f;
        for (int j = 0; j < ENC; ++j) sum += __expf(sS[j] - m);
        float aw = __expf(sS[t] - m) / sum;
        awS[t] = aw;
        covS[t] += aw;
    }
    __syncthreads();
    if (t < HH) {
        float c = 0.f;
        for (int o = 0; o < ENC; ++o) c += awS[o] * encS[o * HH + t];
        ctxS[t] = c;
        xcatS[EE + t] = c;
    }
    if (t >= 128 && t < 256) xcatS[t - 128] = embS[t - 128];
    __syncthreads();

    // ======== x = W_new @ [emb; ctx1] + b_new ========
    matvec4(g, q, HH, EE + HH, W_new, EE + HH, b_new, xcatS, xS);
    __syncthreads();

    // ======== GRU (gate order r, z, n) ========
    matvec4(g, q, 3 * HH, HH, w_ih, HH, b_ih, xS, giS);
    matvec4(g, q, 3 * HH, HH, w_hh, HH, b_hh, hS, ghS);
    __syncthreads();
    if (t < HH) {
        float r = sigmoid_fast(giS[t] + ghS[t]);
        float z = sigmoid_fast(giS[HH + t] + ghS[HH + t]);
        float n = tanh_fast(giS[2 * HH + t] + r * ghS[2 * HH + t]);
        float hn = (1.f - z) * n + z * hS[t];
        h2S[t] = hn;
        out_hidden[b * HH + t] = hn;
    }
    __syncthreads();

    // ======== attention pass 2 (covS now = cov1) ========
    matvec4(g, q, HH, HH, W_dec, HH, b_dec, h2S, decS);
    matvec4(g, q, ENC, ENC, cvgw47, ENC, cvg_b, covS, cvgS);
    __syncthreads();
    {
        int e = g;
        float base = attn_b[e] + cvgS[e];
        const float* efr = &efS[e * HH];
        float s = 0.f;
        for (int m = q; m < 24; m += 4) {
            #pragma unroll
            for (int u = 0; u < 4; ++u) {
                int xx = 4 * m + u;
                s += tanh_fast(efr[xx] + decS[xx] + base) * vS[xx];
            }
        }
        s += __shfl_xor(s, 1); s += __shfl_xor(s, 2);
        if (q == 0) sS[e] = s;
    }
    __syncthreads();
    if (t < ENC) {
        float m = -1e30f;
        for (int j = 0; j < ENC; ++j) m = fmaxf(m, sS[j]);
        float sum = 0.f;
        for (int j = 0; j < ENC; ++j) sum += __expf(sS[j] - m);
        float aw = __expf(sS[t] - m) / sum;
        awS[t] = aw;
        covS[t] += aw;
        out_aw2[b * ENC + t]  = aw;
        out_cov2[b * ENC + t] = covS[t];
    }
    __syncthreads();
    if (t < HH) {
        float c = 0.f;
        for (int o = 0; o < ENC; ++o) c += awS[o] * encS[o * HH + t];
        ctx2S[t] = c;
        out_ctx2[b * HH + t] = c;
        xcatS[t] = h2S[t];
        xcatS[HH + t] = c;
    }
    __syncthreads();

    // ======== o = tanh(W_pre @ [h2; ctx2] + b_pre) ========
    for (int j = g; j < HH; j += 64) {
        const float* wr = W_pre + (size_t)j * (2 * HH);
        float s = 0.f;
        for (int m = q; m < (2 * HH) / 4; m += 4) {
            float4 wq = *(const float4*)(wr + 4 * m);
            s += wq.x * xcatS[4 * m] + wq.y * xcatS[4 * m + 1]
               + wq.z * xcatS[4 * m + 2] + wq.w * xcatS[4 * m + 3];
        }
        s += __shfl_xor(s, 1); s += __shfl_xor(s, 2);
        if (q == 0) oG[b * HH + j] = tanh_fast(s + b_pre[j]);
    }
}

// ---------------------------------------------------------------------------
// K2: logits[b,v] = o[b,:] @ W_out[v,:] + b_out[v], fp32 directly into d_out
// 250 blocks x 128 threads (was 125x256): ~1 block/CU -> all 256 CUs covered.
// ---------------------------------------------------------------------------
__global__ __launch_bounds__(128) void k_logits(
    const float* __restrict__ oG, const float* __restrict__ W_out,
    const float* __restrict__ b_out, float* __restrict__ logits)
{
    __shared__ __align__(16) float oS[BB * HH];
    for (int i = threadIdx.x; i < BB * HH; i += 128) oS[i] = oG[i];
    __syncthreads();

    int v = blockIdx.x * 128 + threadIdx.x;   // 250*128 == 32000
    const float4* row = (const float4*)(W_out + (size_t)v * HH);
    float acc[BB];
    #pragma unroll
    for (int b = 0; b < BB; ++b) acc[b] = 0.f;

    #pragma unroll 6
    for (int c = 0; c < HH / 4; ++c) {
        float4 qv = row[c];
        #pragma unroll
        for (int b = 0; b < BB; ++b) {
            const float4 o0 = *(const float4*)&oS[b * HH + c * 4];
            acc[b] += qv.x * o0.x + qv.y * o0.y + qv.z * o0.z + qv.w * o0.w;
        }
    }
    float bo = b_out[v];
    #pragma unroll
    for (int b = 0; b < BB; ++b) logits[b * VV + v] = acc[b] + bo;
}

// ---------------------------------------------------------------------------
// K3: in-place fp32 log_softmax (4-way unrolled reductions for MLP)
// ---------------------------------------------------------------------------
__global__ __launch_bounds__(1024) void k_logsoftmax(float* __restrict__ out)
{
    int b = blockIdx.x, t = threadIdx.x;
    float* row = out + (size_t)b * VV;
    __shared__ float red[1024];

    float m0 = -1e30f, m1 = -1e30f, m2 = -1e30f, m3 = -1e30f;
    int v = t;
    for (; v + 3072 < VV; v += 4096) {
        m0 = fmaxf(m0, row[v]);
        m1 = fmaxf(m1, row[v + 1024]);
        m2 = fmaxf(m2, row[v + 2048]);
        m3 = fmaxf(m3, row[v + 3072]);
    }
    for (; v < VV; v += 1024) m0 = fmaxf(m0, row[v]);
    red[t] = fmaxf(fmaxf(m0, m1), fmaxf(m2, m3));
    __syncthreads();
    for (int s = 512; s > 0; s >>= 1) {
        if (t < s) red[t] = fmaxf(red[t], red[t + s]);
        __syncthreads();
    }
    float m = red[0]; __syncthreads();

    float s0 = 0.f, s1 = 0.f, s2 = 0.f, s3 = 0.f;
    v = t;
    for (; v + 3072 < VV; v += 4096) {
        s0 += __expf(row[v] - m);
        s1 += __expf(row[v + 1024] - m);
        s2 += __expf(row[v + 2048] - m);
        s3 += __expf(row[v + 3072] - m);
    }
    for (; v < VV; v += 1024) s0 += __expf(row[v] - m);
    red[t] = (s0 + s1) + (s2 + s3);
    __syncthreads();
    for (int s = 512; s > 0; s >>= 1) {
        if (t < s) red[t] += red[t + s];
        __syncthreads();
    }
    float logZ = m + logf(red[0]);

    for (v = t; v < VV; v += 1024) row[v] = row[v] - logZ;
}

// ---------------------------------------------------------------------------
extern "C" void kernel_launch(void* const* d_in, const int* in_sizes, int n_in,
                              void* d_out, int out_size, void* d_ws, size_t ws_size,
                              hipStream_t stream) {
    const float* enc    = (const float*)d_in[0];
    const int*   ids    = (const int*)d_in[1];
    const float* hidden = (const float*)d_in[2];
    const float* cover  = (const float*)d_in[3];
    const float* emb    = (const float*)d_in[4];
    const float* W_dec  = (const float*)d_in[5];
    const float* b_dec  = (const float*)d_in[6];
    const float* attn_w = (const float*)d_in[7];
    const float* attn_b = (const float*)d_in[8];
    const float* cvg_w  = (const float*)d_in[9];
    const float* cvg_b  = (const float*)d_in[10];
    const float* vvec   = (const float*)d_in[11];
    const float* W_new  = (const float*)d_in[12];
    const float* b_new  = (const float*)d_in[13];
    const float* w_ih   = (const float*)d_in[14];
    const float* w_hh   = (const float*)d_in[15];
    const float* b_ih   = (const float*)d_in[16];
    const float* b_hh   = (const float*)d_in[17];
    const float* W_pre  = (const float*)d_in[18];
    const float* b_pre  = (const float*)d_in[19];
    const float* W_out  = (const float*)d_in[20];
    const float* b_out  = (const float*)d_in[21];

    // ws (floats): [0..1536) oG | [1536..5632) cvgw47 | [5632..792064) part
    float* wsf    = (float*)d_ws;
    float* oG     = wsf;
    float* cvgw47 = wsf + 1536;
    float* part   = wsf + 5632;        // 8*16*64*96 = 786432 floats (~3 MB)

    float* out        = (float*)d_out;
    float* out_logp   = out;               // 512000 (logits in place)
    float* out_hidden = out + 512000;
    float* out_ctx2   = out + 513536;
    float* out_aw2    = out + 515072;
    float* out_cov2   = out + 516096;

    k_encfeat<<<1024, 128, 0, stream>>>(enc, attn_w, cvg_w, part, cvgw47);
    k_fused<<<16, 256, 0, stream>>>(enc, ids, hidden, cover, emb, W_dec, b_dec,
                                    attn_b, cvgw47, cvg_b, vvec, W_new, b_new,
                                    w_ih, w_hh, b_ih, b_hh, W_pre, b_pre,
                                    part, oG,
                                    out_hidden, out_ctx2, out_aw2, out_cov2);
    k_logits<<<250, 128, 0, stream>>>(oG, W_out, b_out, out_logp);
    k_logsoftmax<<<16, 1024, 0, stream>>>(out_logp);
}

// Round 2
// 345.173 us; speedup vs baseline: 1.0435x; 1.0032x over previous
//
#include <hip/hip_runtime.h>

#define BB 16
#define ENC 64
#define HH 96
#define EE 128
#define VV 32000

__device__ __forceinline__ float tanh_fast(float x) {
    // exact at saturation: exp(2x)->inf => 1; ->0 => -1
    float e = __expf(2.f * x);
    return 1.f - 2.f / (e + 1.f);
}
__device__ __forceinline__ float sigmoid_fast(float x) {
    return 1.f / (1.f + __expf(-x));
}

// ---------------------------------------------------------------------------
// K0: partial enc_feat. part[ic][b][o][x] = sum_{i in chunk, kw} attn_w[o,i,47,kw]
//     * encpad[b,i,x+kw].  (conv kh collapses to 47: input height 1, pad(47,48))
// grid 1024 = b(16) * otile(4; 16 o) * ichunk(16; 4 i), 128 threads (2 waves).
// Lane tile: 1 o-row x 12 x-cols. 64 lanes = 8 og x 8 xstrips — full wave.
// Rolling 4xfloat4 E window: per k-quad = 1 W b128 + 1 E b128 + 48 FMA.
// Wb rows padded to 100 floats: og lanes hit distinct bank quads (broadcast x8).
// E strips stride 12: start banks {0,12,24,4,16,28,8,20} — conflict-free.
// Blocks with b==0,ot==0,ic<8 also extract cvg_w[:,:,0,47] -> cvgw47.
// ---------------------------------------------------------------------------
#define STEP(q, wa, wb_, wc_, wd_) do { \
    accA.x += q.x*wa.x  + q.y*wa.y  + q.z*wa.z  + q.w*wa.w;  \
    accA.y += q.x*wa.y  + q.y*wa.z  + q.z*wa.w  + q.w*wb_.x; \
    accA.z += q.x*wa.z  + q.y*wa.w  + q.z*wb_.x + q.w*wb_.y; \
    accA.w += q.x*wa.w  + q.y*wb_.x + q.z*wb_.y + q.w*wb_.z; \
    accB.x += q.x*wb_.x + q.y*wb_.y + q.z*wb_.z + q.w*wb_.w; \
    accB.y += q.x*wb_.y + q.y*wb_.z + q.z*wb_.w + q.w*wc_.x; \
    accB.z += q.x*wb_.z + q.y*wb_.w + q.z*wc_.x + q.w*wc_.y; \
    accB.w += q.x*wb_.w + q.y*wc_.x + q.z*wc_.y + q.w*wc_.z; \
    accC.x += q.x*wc_.x + q.y*wc_.y + q.z*wc_.z + q.w*wc_.w; \
    accC.y += q.x*wc_.y + q.y*wc_.z + q.z*wc_.w + q.w*wd_.x; \
    accC.z += q.x*wc_.z + q.y*wc_.w + q.z*wd_.x + q.w*wd_.y; \
    accC.w += q.x*wc_.w + q.y*wd_.x + q.z*wd_.y + q.w*wd_.z; \
} while (0)

__global__ __launch_bounds__(128) void k_encfeat(
    const float* __restrict__ enc,      // (B,ENC,H)
    const float* __restrict__ attn_w,   // (ENC,ENC,H,H)
    const float* __restrict__ cvg_w,    // (ENC,ENC,1,H)
    float* __restrict__ part,           // (16,B,ENC,H) partial sums
    float* __restrict__ cvgw47)         // (ENC,ENC)
{
    int blk = blockIdx.x;
    int b   = blk >> 6;          // 16
    int ot  = (blk >> 4) & 3;    // 4  (16 o each)
    int ic  = blk & 15;          // 16 (4 i each)
    int o0  = ot * 16;
    int i0  = ic * 4;
    int t   = threadIdx.x;

    __shared__ __align__(16) float encS[4 * 208];      // [47 zero | 96 enc | 65 zero]
    __shared__ __align__(16) float Wb[4 * 16 * 100];   // [i][o16][k], stride 100

    // zero encS (832 floats = 208 f4)
    for (int f = t; f < 208; f += 128)
        ((float4*)encS)[f] = make_float4(0.f, 0.f, 0.f, 0.f);
    __syncthreads();
    for (int f = t; f < 4 * 96; f += 128) {
        int i = f / 96, j = f - i * 96;
        encS[i * 208 + 47 + j] = enc[(size_t)((b * ENC + i0 + i) * 96) + j];
    }
    // stage weights: 16o x 4i x 96k = 1536 float4 (12 per thread)
    for (int F = t; F < 1536; F += 128) {
        int o = F / 96;
        int r = F - o * 96;
        int i = r / 24, kq = r - i * 24;
        float4 q = *(const float4*)(attn_w +
            (size_t)((o0 + o) * ENC + (i0 + i)) * (96 * 96) + 47 * 96 + 4 * kq);
        *(float4*)&Wb[(i * 16 + o) * 100 + 4 * kq] = q;
    }
    // side job: cvgw47 extraction (8 blocks cover 4096 elems)
    if (b == 0 && ot == 0 && ic < 8) {
        #pragma unroll
        for (int j = 0; j < 4; ++j) {
            int e = ic * 512 + j * 128 + t;
            cvgw47[e] = cvg_w[(size_t)e * 96 + 47];
        }
    }
    __syncthreads();

    int w    = t >> 6;            // wave -> o half (8 rows)
    int ln   = t & 63;
    int og   = ln & 7;
    int xs   = ln >> 3;           // 8 strips of 12
    int x0   = xs * 12;
    int orow = w * 8 + og;        // 0..15 within o-tile

    float4 accA = make_float4(0.f, 0.f, 0.f, 0.f);
    float4 accB = make_float4(0.f, 0.f, 0.f, 0.f);
    float4 accC = make_float4(0.f, 0.f, 0.f, 0.f);

    for (int i = 0; i < 4; ++i) {
        const float* er = &encS[i * 208 + x0];
        const float* wr = &Wb[(i * 16 + orow) * 100];
        float4 e0 = *(const float4*)(er);
        float4 e1 = *(const float4*)(er + 4);
        float4 e2 = *(const float4*)(er + 8);
        float4 e3 = *(const float4*)(er + 12);
        #pragma unroll
        for (int cb = 0; cb < 6; ++cb) {
            float4 q0 = *(const float4*)(wr + 16 * cb);
            float4 q1 = *(const float4*)(wr + 16 * cb + 4);
            float4 q2 = *(const float4*)(wr + 16 * cb + 8);
            float4 q3 = *(const float4*)(wr + 16 * cb + 12);
            STEP(q0, e0, e1, e2, e3);
            e0 = *(const float4*)(er + 16 * cb + 16);
            STEP(q1, e1, e2, e3, e0);
            e1 = *(const float4*)(er + 16 * cb + 20);
            STEP(q2, e2, e3, e0, e1);
            e2 = *(const float4*)(er + 16 * cb + 24);
            STEP(q3, e3, e0, e1, e2);
            e3 = *(const float4*)(er + 16 * cb + 28);
        }
    }
    float* outr = part + ((size_t)(ic * 16 + b) * 64 + o0 + orow) * 96 + x0;
    *(float4*)(outr)     = accA;
    *(float4*)(outr + 4) = accB;
    *(float4*)(outr + 8) = accC;
}

// ---------------------------------------------------------------------------
// cooperative matvec: 4 lanes per output row, float4 loads, shuffle reduce.
// ---------------------------------------------------------------------------
__device__ __forceinline__ void matvec4(int g, int q, int nout, int nk,
    const float* __restrict__ W, int ldw, const float* __restrict__ bias,
    const float* __restrict__ xv, float* __restrict__ y)
{
    for (int j = g; j < nout; j += 64) {
        const float* wr = W + (size_t)j * ldw;
        float s = 0.f;
        for (int m = q; m < nk / 4; m += 4) {
            float4 wq = *(const float4*)(wr + 4 * m);
            s += wq.x * xv[4 * m] + wq.y * xv[4 * m + 1]
               + wq.z * xv[4 * m + 2] + wq.w * xv[4 * m + 3];
        }
        s += __shfl_xor(s, 1);
        s += __shfl_xor(s, 2);
        if (q == 0) y[j] = s + bias[j];
    }
}

// ---------------------------------------------------------------------------
// K1: fused attn1 + GRU + attn2 + pre-output, one block (256 thr) per b.
// ---------------------------------------------------------------------------
__global__ __launch_bounds__(256) void k_fused(
    const float* __restrict__ enc, const int* __restrict__ ids,
    const float* __restrict__ hidden, const float* __restrict__ coverage,
    const float* __restrict__ emb,
    const float* __restrict__ W_dec, const float* __restrict__ b_dec,
    const float* __restrict__ attn_b,
    const float* __restrict__ cvgw47, const float* __restrict__ cvg_b,
    const float* __restrict__ vvec,
    const float* __restrict__ W_new, const float* __restrict__ b_new,
    const float* __restrict__ w_ih, const float* __restrict__ w_hh,
    const float* __restrict__ b_ih, const float* __restrict__ b_hh,
    const float* __restrict__ W_pre, const float* __restrict__ b_pre,
    const float* __restrict__ part, float* __restrict__ oG,
    float* __restrict__ out_hidden, float* __restrict__ out_ctx2,
    float* __restrict__ out_aw2, float* __restrict__ out_cov2)
{
    int b = blockIdx.x, t = threadIdx.x;
    int g = t >> 2, q = t & 3;

    __shared__ __align__(16) float efS[ENC * HH];    // summed enc_feat slice
    __shared__ __align__(16) float encS[ENC * HH];   // enc slice
    __shared__ float hS[HH], vS[HH], decS[HH], ctxS[HH], xS[HH], h2S[HH], ctx2S[HH];
    __shared__ float covS[ENC], cvgS[ENC], sS[ENC], awS[ENC];
    __shared__ float embS[EE];
    __shared__ __align__(16) float xcatS[EE + HH];
    __shared__ float giS[3 * HH], ghS[3 * HH];

    {   // vectorized 16-way partial sum + enc staging (1536 float4)
        const float4* enc4 = (const float4*)(enc + (size_t)b * ENC * HH);
        float4* efS4  = (float4*)efS;
        float4* encS4 = (float4*)encS;
        for (int f = t; f < (ENC * HH) / 4; f += 256) {
            float4 s = make_float4(0.f, 0.f, 0.f, 0.f);
            #pragma unroll
            for (int ic = 0; ic < 16; ++ic) {
                const float4 p = *(const float4*)(part +
                    (size_t)(ic * 16 + b) * (ENC * HH) + 4 * f);
                s.x += p.x; s.y += p.y; s.z += p.z; s.w += p.w;
            }
            efS4[f]  = s;
            encS4[f] = enc4[f];
        }
    }
    if (t < HH) { hS[t] = hidden[b * HH + t]; vS[t] = vvec[b * HH + t]; }
    if (t >= 96 && t < 160) covS[t - 96] = coverage[b * ENC + (t - 96)];
    if (t >= 128 && t < 256) embS[t - 128] = emb[(size_t)ids[b] * EE + (t - 128)];
    __syncthreads();

    // ======== attention pass 1 ========
    matvec4(g, q, HH, HH, W_dec, HH, b_dec, hS, decS);
    matvec4(g, q, ENC, ENC, cvgw47, ENC, cvg_b, covS, cvgS);
    __syncthreads();
    {
        int e = g;
        float base = attn_b[e] + cvgS[e];
        const float* efr = &efS[e * HH];
        float s = 0.f;
        for (int m = q; m < 24; m += 4) {
            #pragma unroll
            for (int u = 0; u < 4; ++u) {
                int xx = 4 * m + u;
                s += tanh_fast(efr[xx] + decS[xx] + base) * vS[xx];
            }
        }
        s += __shfl_xor(s, 1); s += __shfl_xor(s, 2);
        if (q == 0) sS[e] = s;
    }
    __syncthreads();
    if (t < ENC) {
        float m = -1e30f;
        for (int j = 0; j < ENC; ++j) m = fmaxf(m, sS[j]);
        float sum = 0.f;
        for (int j = 0; j < ENC; ++j) sum += __expf(sS[j] - m);
        float aw = __expf(sS[t] - m) / sum;
        awS[t] = aw;
        covS[t] += aw;
    }
    __syncthreads();
    if (t < HH) {
        float c = 0.f;
        for (int o = 0; o < ENC; ++o) c += awS[o] * encS[o * HH + t];
        ctxS[t] = c;
        xcatS[EE + t] = c;
    }
    if (t >= 128 && t < 256) xcatS[t - 128] = embS[t - 128];
    __syncthreads();

    // ======== x = W_new @ [emb; ctx1] + b_new ========
    matvec4(g, q, HH, EE + HH, W_new, EE + HH, b_new, xcatS, xS);
    __syncthreads();

    // ======== GRU (gate order r, z, n) ========
    matvec4(g, q, 3 * HH, HH, w_ih, HH, b_ih, xS, giS);
    matvec4(g, q, 3 * HH, HH, w_hh, HH, b_hh, hS, ghS);
    __syncthreads();
    if (t < HH) {
        float r = sigmoid_fast(giS[t] + ghS[t]);
        float z = sigmoid_fast(giS[HH + t] + ghS[HH + t]);
        float n = tanh_fast(giS[2 * HH + t] + r * ghS[2 * HH + t]);
        float hn = (1.f - z) * n + z * hS[t];
        h2S[t] = hn;
        out_hidden[b * HH + t] = hn;
    }
    __syncthreads();

    // ======== attention pass 2 (covS now = cov1) ========
    matvec4(g, q, HH, HH, W_dec, HH, b_dec, h2S, decS);
    matvec4(g, q, ENC, ENC, cvgw47, ENC, cvg_b, covS, cvgS);
    __syncthreads();
    {
        int e = g;
        float base = attn_b[e] + cvgS[e];
        const float* efr = &efS[e * HH];
        float s = 0.f;
        for (int m = q; m < 24; m += 4) {
            #pragma unroll
            for (int u = 0; u < 4; ++u) {
                int xx = 4 * m + u;
                s += tanh_fast(efr[xx] + decS[xx] + base) * vS[xx];
            }
        }
        s += __shfl_xor(s, 1); s += __shfl_xor(s, 2);
        if (q == 0) sS[e] = s;
    }
    __syncthreads();
    if (t < ENC) {
        float m = -1e30f;
        for (int j = 0; j < ENC; ++j) m = fmaxf(m, sS[j]);
        float sum = 0.f;
        for (int j = 0; j < ENC; ++j) sum += __expf(sS[j] - m);
        float aw = __expf(sS[t] - m) / sum;
        awS[t] = aw;
        covS[t] += aw;
        out_aw2[b * ENC + t]  = aw;
        out_cov2[b * ENC + t] = covS[t];
    }
    __syncthreads();
    if (t < HH) {
        float c = 0.f;
        for (int o = 0; o < ENC; ++o) c += awS[o] * encS[o * HH + t];
        ctx2S[t] = c;
        out_ctx2[b * HH + t] = c;
        xcatS[t] = h2S[t];
        xcatS[HH + t] = c;
    }
    __syncthreads();

    // ======== o = tanh(W_pre @ [h2; ctx2] + b_pre) ========
    for (int j = g; j < HH; j += 64) {
        const float* wr = W_pre + (size_t)j * (2 * HH);
        float s = 0.f;
        for (int m = q; m < (2 * HH) / 4; m += 4) {
            float4 wq = *(const float4*)(wr + 4 * m);
            s += wq.x * xcatS[4 * m] + wq.y * xcatS[4 * m + 1]
               + wq.z * xcatS[4 * m + 2] + wq.w * xcatS[4 * m + 3];
        }
        s += __shfl_xor(s, 1); s += __shfl_xor(s, 2);
        if (q == 0) oG[b * HH + j] = tanh_fast(s + b_pre[j]);
    }
}

// ---------------------------------------------------------------------------
// K2: logits[b,v] = o[b,:] @ W_out[v,:] + b_out[v], fp32 directly into d_out
// 250 blocks x 128 threads: ~1 block/CU -> all 256 CUs covered.
// ---------------------------------------------------------------------------
__global__ __launch_bounds__(128) void k_logits(
    const float* __restrict__ oG, const float* __restrict__ W_out,
    const float* __restrict__ b_out, float* __restrict__ logits)
{
    __shared__ __align__(16) float oS[BB * HH];
    for (int i = threadIdx.x; i < BB * HH; i += 128) oS[i] = oG[i];
    __syncthreads();

    int v = blockIdx.x * 128 + threadIdx.x;   // 250*128 == 32000
    const float4* row = (const float4*)(W_out + (size_t)v * HH);
    float acc[BB];
    #pragma unroll
    for (int b = 0; b < BB; ++b) acc[b] = 0.f;

    #pragma unroll 6
    for (int c = 0; c < HH / 4; ++c) {
        float4 qv = row[c];
        #pragma unroll
        for (int b = 0; b < BB; ++b) {
            const float4 o0 = *(const float4*)&oS[b * HH + c * 4];
            acc[b] += qv.x * o0.x + qv.y * o0.y + qv.z * o0.z + qv.w * o0.w;
        }
    }
    float bo = b_out[v];
    #pragma unroll
    for (int b = 0; b < BB; ++b) logits[b * VV + v] = acc[b] + bo;
}

// ---------------------------------------------------------------------------
// K3: in-place fp32 log_softmax. Row cached in 8 float4 regs: ONE global read
// + one write (was 3 reads + 1 write). 32000 = 7*4096 + tail(832 f4).
// ---------------------------------------------------------------------------
#define MAX4(r) fmaxf(fmaxf((r).x, (r).y), fmaxf((r).z, (r).w))
__global__ __launch_bounds__(1024) void k_logsoftmax(float* __restrict__ out)
{
    int b = blockIdx.x, t = threadIdx.x;
    float* row = out + (size_t)b * VV;
    const float4* row4 = (const float4*)row;
    float4* row4w = (float4*)row;
    __shared__ float red[1024];

    float4 c0, c1, c2, c3, c4, c5, c6, c7;
    bool has7 = (t < 8000 - 7 * 1024);   // t < 832
    c0 = row4[t];
    c1 = row4[t + 1024];
    c2 = row4[t + 2048];
    c3 = row4[t + 3072];
    c4 = row4[t + 4096];
    c5 = row4[t + 5120];
    c6 = row4[t + 6144];
    float m0 = fmaxf(fmaxf(MAX4(c0), MAX4(c1)),
                     fmaxf(fmaxf(MAX4(c2), MAX4(c3)),
                           fmaxf(MAX4(c4), fmaxf(MAX4(c5), MAX4(c6)))));
    if (has7) { c7 = row4[t + 7168]; m0 = fmaxf(m0, MAX4(c7)); }
    red[t] = m0;
    __syncthreads();
    for (int s = 512; s > 0; s >>= 1) {
        if (t < s) red[t] = fmaxf(red[t], red[t + s]);
        __syncthreads();
    }
    float m = red[0]; __syncthreads();

    float s0 = 0.f;
    #define ESUM(r) (__expf((r).x - m) + __expf((r).y - m) + \
                     __expf((r).z - m) + __expf((r).w - m))
    s0 = ESUM(c0) + ESUM(c1) + ESUM(c2) + ESUM(c3)
       + ESUM(c4) + ESUM(c5) + ESUM(c6);
    if (has7) s0 += ESUM(c7);
    red[t] = s0;
    __syncthreads();
    for (int s = 512; s > 0; s >>= 1) {
        if (t < s) red[t] += red[t + s];
        __syncthreads();
    }
    float logZ = m + logf(red[0]);

    #define SUB4(r) { (r).x -= logZ; (r).y -= logZ; (r).z -= logZ; (r).w -= logZ; }
    SUB4(c0); SUB4(c1); SUB4(c2); SUB4(c3); SUB4(c4); SUB4(c5); SUB4(c6);
    row4w[t]        = c0;
    row4w[t + 1024] = c1;
    row4w[t + 2048] = c2;
    row4w[t + 3072] = c3;
    row4w[t + 4096] = c4;
    row4w[t + 5120] = c5;
    row4w[t + 6144] = c6;
    if (has7) { SUB4(c7); row4w[t + 7168] = c7; }
}

// ---------------------------------------------------------------------------
extern "C" void kernel_launch(void* const* d_in, const int* in_sizes, int n_in,
                              void* d_out, int out_size, void* d_ws, size_t ws_size,
                              hipStream_t stream) {
    const float* enc    = (const float*)d_in[0];
    const int*   ids    = (const int*)d_in[1];
    const float* hidden = (const float*)d_in[2];
    const float* cover  = (const float*)d_in[3];
    const float* emb    = (const float*)d_in[4];
    const float* W_dec  = (const float*)d_in[5];
    const float* b_dec  = (const float*)d_in[6];
    const float* attn_w = (const float*)d_in[7];
    const float* attn_b = (const float*)d_in[8];
    const float* cvg_w  = (const float*)d_in[9];
    const float* cvg_b  = (const float*)d_in[10];
    const float* vvec   = (const float*)d_in[11];
    const float* W_new  = (const float*)d_in[12];
    const float* b_new  = (const float*)d_in[13];
    const float* w_ih   = (const float*)d_in[14];
    const float* w_hh   = (const float*)d_in[15];
    const float* b_ih   = (const float*)d_in[16];
    const float* b_hh   = (const float*)d_in[17];
    const float* W_pre  = (const float*)d_in[18];
    const float* b_pre  = (const float*)d_in[19];
    const float* W_out  = (const float*)d_in[20];
    const float* b_out  = (const float*)d_in[21];

    // ws (floats): [0..1536) oG | [1536..5632) cvgw47 | [5632..1578496) part
    float* wsf    = (float*)d_ws;
    float* oG     = wsf;
    float* cvgw47 = wsf + 1536;
    float* part   = wsf + 5632;        // 16*16*64*96 = 1572864 floats (~6.3 MB)

    float* out        = (float*)d_out;
    float* out_logp   = out;               // 512000 (logits in place)
    float* out_hidden = out + 512000;
    float* out_ctx2   = out + 513536;
    float* out_aw2    = out + 515072;
    float* out_cov2   = out + 516096;

    k_encfeat<<<1024, 128, 0, stream>>>(enc, attn_w, cvg_w, part, cvgw47);
    k_fused<<<16, 256, 0, stream>>>(enc, ids, hidden, cover, emb, W_dec, b_dec,
                                    attn_b, cvgw47, cvg_b, vvec, W_new, b_new,
                                    w_ih, w_hh, b_ih, b_hh, W_pre, b_pre,
                                    part, oG,
                                    out_hidden, out_ctx2, out_aw2, out_cov2);
    k_logits<<<250, 128, 0, stream>>>(oG, W_out, b_out, out_logp);
    k_logsoftmax<<<16, 1024, 0, stream>>>(out_logp);
}